// Round 14
// baseline (421.613 us; speedup 1.0000x reference)
//
#include <hip/hip_runtime.h>
#include <math.h>

namespace {

constexpr int B_ = 8, C_ = 256, H_ = 128, W_ = 192;
constexpr int HW = H_ * W_;
constexpr size_t CHW = (size_t)C_ * HW;
constexpr int TH = 8, TW = 16;          // block tile
constexpr int NTHREADS = 512;           // 8 waves, wave = h row
constexpr int KSUP = 32;                // ch per super-chunk (one K=32 MFMA)
constexpr int NSUP = C_ / KSUP;         // 8
constexpr int BROWS = 16;               // staged f2 rows h0-4 .. h0+11
constexpr int BPOS = 24;                // staged f2 cols w0-4 .. w0+19 (overlapped tiles)
constexpr int POSB = 80;                // 64B data (32ch f16) + 16B pad
constexpr int ROWB = BPOS * POSB + 16;  // 1936: +16 row pad (odd slot count)
constexpr int BUFB = BROWS * ROWB;      // 30976 per buffer
constexpr int LDSB = 2 * BUFB;          // 61952 -> 2 blocks/CU
constexpr int NSTG = BROWS * BPOS;      // 384 staging threads
constexpr int OSTR = 20;                // out-LDS dwords/row
constexpr int OUTB = 81 * 4 * OSTR * 4; // 25920 (one h-half)
constexpr int BNOFF = OUTB;             // f2 norms [16][24] f32 overlay (in buf0)

typedef _Float16 f16x8 __attribute__((ext_vector_type(8)));
typedef float f32x4 __attribute__((ext_vector_type(4)));
typedef _Float16 h2 __attribute__((ext_vector_type(2)));

__device__ __forceinline__ unsigned pk2(float x, float y) {
    return __builtin_bit_cast(unsigned, __builtin_amdgcn_cvt_pkrtz(x, y));
}
__device__ __forceinline__ float dot2f(unsigned a, unsigned b, float c) {
#if __has_builtin(__builtin_amdgcn_fdot2)
    return __builtin_amdgcn_fdot2(__builtin_bit_cast(h2, a),
                                  __builtin_bit_cast(h2, b), c, false);
#else
    const h2 ha = __builtin_bit_cast(h2, a), hb = __builtin_bit_cast(h2, b);
    return fmaf((float)ha.x, (float)hb.x, fmaf((float)ha.y, (float)hb.y, c));
#endif
}

// Raw publish barrier: drains LDS counts only; global loads stay in flight.
__device__ __forceinline__ void publish_barrier() {
    asm volatile("s_waitcnt lgkmcnt(0)" ::: "memory");
    __builtin_amdgcn_sched_barrier(0);
    __builtin_amdgcn_s_barrier();
    __builtin_amdgcn_sched_barrier(0);
}

__global__ __launch_bounds__(NTHREADS)
void local_corr_mfma(const float* __restrict__ f1g,
                     const float* __restrict__ f2g,
                     float* __restrict__ outg)
{
    __shared__ __align__(16) char lds[LDSB];

    // XCD swizzle: image = XCD id
    const int m  = blockIdx.x;          // 0..1535
    const int b  = m & 7;
    const int k  = m >> 3;              // 0..191
    const int bx = k % 12;
    const int by = k / 12;              // 0..15
    const int w0 = bx * TW, h0 = by * TH;

    const int tid  = threadIdx.x;
    const int hs   = tid >> 6;          // wave = h row 0..7
    const int lane = tid & 63;
    const int lp   = lane & 15;         // fragment pos
    const int lg   = lane >> 4;         // k-group (ch 8*lg..8*lg+7 per super)

    // ---- B staging: threads 0..383 own one staged f2 position (sr, sp) ----
    const bool isStage = tid < NSTG;    // waves 0-5 stage; waves 6,7 compute-only
    const int sr = tid / BPOS;          // 0..15
    const int sp = tid % BPOS;          // 0..23
    const int bgh = h0 - 4 + sr, bgw = w0 - 4 + sp;
    const bool bok = isStage && (bgh >= 0) && (bgh < H_) && (bgw >= 0) && (bgw < W_);
    const int bghc = min(max(bgh, 0), H_ - 1);
    const int bgwc = min(max(bgw, 0), W_ - 1);
    const float* bbase = f2g + (size_t)b * CHW + (size_t)bghc * W_ + bgwc;
    // ---- A direct-from-global: lane (lp,lg) owns f1[h0+hs][w0+lp], ch 8lg+j ----
    const float* abase = f1g + (size_t)b * CHW + (size_t)(h0 + hs) * W_ + (w0 + lp)
                             + (size_t)(8 * lg) * HW;

    float bvr[16], avr[4];
    unsigned aw[4];                     // packed A frag (current super-chunk)
    float bn = 0.f, an = 0.f;

    auto issueB = [&](int c0) {
        if (!isStage) return;
#pragma unroll
        for (int j = 0; j < 16; ++j) bvr[j] = bbase[(size_t)(c0 + j) * HW];
    };
    auto issueA = [&](int c0) {         // c0 = 32*s + 4*h (8lg folded in abase)
#pragma unroll
        for (int j = 0; j < 4; ++j) avr[j] = abase[(size_t)(c0 + j) * HW];
    };

    auto stageB = [&](int buf, int h) {
        if (isStage) {
            unsigned u[8];
#pragma unroll
            for (int q = 0; q < 8; ++q) {
                const float x = bok ? bvr[2 * q] : 0.f;
                const float y = bok ? bvr[2 * q + 1] : 0.f;
                u[q] = pk2(x, y);
                bn = dot2f(u[q], u[q], bn);
            }
            char* dst = lds + buf * BUFB + sr * ROWB + sp * POSB + 32 * h;
            *reinterpret_cast<uint4*>(dst)      = make_uint4(u[0], u[1], u[2], u[3]);
            *reinterpret_cast<uint4*>(dst + 16) = make_uint4(u[4], u[5], u[6], u[7]);
        }
        const unsigned a0 = pk2(avr[0], avr[1]);
        const unsigned a1 = pk2(avr[2], avr[3]);
        an = dot2f(a0, a0, an);
        an = dot2f(a1, a1, an);
        aw[2 * h] = a0;
        aw[2 * h + 1] = a1;
    };

    f32x4 acc[9][2];
#pragma unroll
    for (int dy = 0; dy < 9; ++dy)
#pragma unroll
        for (int bt = 0; bt < 2; ++bt) acc[dy][bt] = (f32x4)0.f;

    const int fro = lp * POSB + lg * 16;   // b128 read offset (16B aligned)

    auto compute = [&](int buf) {
        const f16x8 afrag = __builtin_bit_cast(f16x8, make_uint4(aw[0], aw[1], aw[2], aw[3]));
        __builtin_amdgcn_s_setprio(1);
#pragma unroll
        for (int dy = 0; dy < 9; ++dy) {
            const char* rbase = lds + buf * BUFB + (hs + dy) * ROWB + fro;
            const f16x8 b0 = *reinterpret_cast<const f16x8*>(rbase);              // pos 0..15
            const f16x8 b1 = *reinterpret_cast<const f16x8*>(rbase + 8 * POSB);   // pos 8..23
            acc[dy][0] = __builtin_amdgcn_mfma_f32_16x16x32_f16(afrag, b0, acc[dy][0], 0, 0, 0);
            acc[dy][1] = __builtin_amdgcn_mfma_f32_16x16x32_f16(afrag, b1, acc[dy][1], 0, 0, 0);
        }
        __builtin_amdgcn_s_setprio(0);
    };

    // ---- pipeline: 8 super-chunks, halves staged into alternating buffers,
    //      raw lgkm-only barriers (2 per super), vmcnt never drained ----
    issueB(0);  issueA(0);
    stageB(0, 0);
    issueB(16); issueA(4);
    stageB(0, 1);
    issueB(32); issueA(32);
    publish_barrier();
    for (int s = 0; s < NSUP; ++s) {
        const int cur = s & 1, nxt = cur ^ 1;
        compute(cur);                       // reads buf cur + aw(s)
        if (s + 1 < NSUP) {
            stageB(nxt, 0);                 // super s+1 lo (loads long in flight)
            issueB(32 * (s + 1) + 16);
            issueA(32 * (s + 1) + 4);
        }
        publish_barrier();
        if (s + 1 < NSUP) {
            stageB(nxt, 1);                 // super s+1 hi
            if (s + 2 < NSUP) { issueB(32 * (s + 2)); issueA(32 * (s + 2)); }
        }
        publish_barrier();
    }

    // ---- norms (buf0 dead -> overlay) ----
    float* bnorm = reinterpret_cast<float*>(lds + BNOFF);   // [16][24]
    if (isStage) bnorm[tid] = bn;
    an += __shfl_xor(an, 16);
    an += __shfl_xor(an, 32);                               // full norm of pos lp
    const float inv1own = 1.0f / fmaxf(sqrtf(an), 1e-12f);
    float inv1v[4];
#pragma unroll
    for (int r = 0; r < 4; ++r) inv1v[r] = __shfl(inv1own, 4 * lg + r);
    __syncthreads();

    // ---- epilogue: overlapped-tile band select (bt = lg>>1, lane-uniform) ----
    const int btsel = lg >> 1;
    const int pos   = lp + 8 * btsel;       // staged f2 position this lane reads
    const size_t obase = (size_t)b * 81 * HW;
#pragma unroll
    for (int pass = 0; pass < 2; ++pass) {
        if ((hs >> 2) == pass) {
            const int h4 = hs & 3;
#pragma unroll
            for (int dy = 0; dy < 9; ++dy) {
                const float nb = bnorm[(hs + dy) * BPOS + pos];
                const float v2 = 1.0f / fmaxf(sqrtf(nb), 1e-12f);
#pragma unroll
                for (int r = 0; r < 4; ++r) {
                    const int mw  = 4 * lg + r;            // f1 w within tile
                    const int dxi = pos - mw;              // dx + 4
                    if (dxi >= 0 && dxi <= 8) {
                        float* orow = reinterpret_cast<float*>(lds)
                                    + ((dy * 9 + dxi) * 4 + h4) * OSTR;
                        orow[mw] = acc[dy][btsel][r] * inv1v[r] * v2;
                    }
                }
            }
        }
        __syncthreads();
        for (int s = tid; s < 81 * 4 * 4; s += NTHREADS) {
            const int od = s >> 4;
            const int rem = s & 15;
            const int h4 = rem >> 2, q = rem & 3;
            const float4 v = *reinterpret_cast<const float4*>(
                reinterpret_cast<const float*>(lds) + (od * 4 + h4) * OSTR + q * 4);
            *reinterpret_cast<float4*>(outg + obase + (size_t)od * HW +
                                       (size_t)(h0 + pass * 4 + h4) * W_ + w0 + q * 4) = v;
        }
        if (pass == 0) __syncthreads();
    }
}

} // namespace

extern "C" void kernel_launch(void* const* d_in, const int* in_sizes, int n_in,
                              void* d_out, int out_size, void* d_ws, size_t ws_size,
                              hipStream_t stream)
{
    (void)in_sizes; (void)n_in; (void)d_ws; (void)ws_size; (void)out_size;
    const float* f1 = (const float*)d_in[0];
    const float* f2 = (const float*)d_in[1];
    float* out = (float*)d_out;

    dim3 grid(1536, 1, 1);     // 8 images x 16 hb x 12 wb, XCD-chunked in kernel
    dim3 block(NTHREADS);      // 512 threads = 8 waves (wave = h row)
    local_corr_mfma<<<grid, block, 0, stream>>>(f1, f2, out);
}

// Round 15
// 197.752 us; speedup vs baseline: 2.1320x; 2.1320x over previous
//
#include <hip/hip_runtime.h>
#include <math.h>

namespace {

constexpr int B_ = 8, C_ = 256, H_ = 128, W_ = 192;
constexpr int HW = H_ * W_;
constexpr size_t CHW = (size_t)C_ * HW;
constexpr int TH = 8, TW = 16;          // block tile
constexpr int NTHREADS = 512;           // 8 waves, wave = h row
constexpr int KSUP = 32;                // ch per super-chunk (one K=32 MFMA)
constexpr int NSUP = C_ / KSUP;         // 8
constexpr int BROWS = 16;               // staged f2 rows h0-4 .. h0+11
constexpr int BPOS = 24;                // staged f2 cols w0-4 .. w0+19 (overlapped tiles)
constexpr int POSB = 80;                // 64B data (32ch f16) + 16B pad
constexpr int ROWB = BPOS * POSB + 16;  // 1936: +16 row pad (odd slot count)
constexpr int BUFB = BROWS * ROWB;      // 30976 per buffer
constexpr int LDSB = 2 * BUFB;          // 61952 -> 2 blocks/CU
constexpr int NSTG = BROWS * BPOS;      // 384 staging threads
constexpr int OSTR = 20;                // out-LDS dwords/row
constexpr int OUTB = 81 * 4 * OSTR * 4; // 25920 (one h-half)
constexpr int BNOFF = OUTB;             // f2 norms [16][24] f32 overlay (in buf0)

typedef _Float16 f16x8 __attribute__((ext_vector_type(8)));
typedef float f32x4 __attribute__((ext_vector_type(4)));
typedef _Float16 h2 __attribute__((ext_vector_type(2)));

__device__ __forceinline__ unsigned pk2(float x, float y) {
    return __builtin_bit_cast(unsigned, __builtin_amdgcn_cvt_pkrtz(x, y));
}
__device__ __forceinline__ float dot2f(unsigned a, unsigned b, float c) {
#if __has_builtin(__builtin_amdgcn_fdot2)
    return __builtin_amdgcn_fdot2(__builtin_bit_cast(h2, a),
                                  __builtin_bit_cast(h2, b), c, false);
#else
    const h2 ha = __builtin_bit_cast(h2, a), hb = __builtin_bit_cast(h2, b);
    return fmaf((float)ha.x, (float)hb.x, fmaf((float)ha.y, (float)hb.y, c));
#endif
}

// Raw publish barrier: drains LDS counts only; global loads stay in flight.
__device__ __forceinline__ void publish_barrier() {
    asm volatile("s_waitcnt lgkmcnt(0)" ::: "memory");
    __builtin_amdgcn_sched_barrier(0);
    __builtin_amdgcn_s_barrier();
    __builtin_amdgcn_sched_barrier(0);
}

__global__ __launch_bounds__(NTHREADS)
void local_corr_mfma(const float* __restrict__ f1g,
                     const float* __restrict__ f2g,
                     float* __restrict__ outg)
{
    __shared__ __align__(16) char lds[LDSB];

    // XCD swizzle: image = XCD id
    const int m  = blockIdx.x;          // 0..1535
    const int b  = m & 7;
    const int k  = m >> 3;              // 0..191
    const int bx = k % 12;
    const int by = k / 12;              // 0..15
    const int w0 = bx * TW, h0 = by * TH;

    const int tid  = threadIdx.x;
    const int hs   = tid >> 6;          // wave = h row 0..7
    const int lane = tid & 63;
    const int lp   = lane & 15;         // fragment pos
    const int lg   = lane >> 4;         // k-group (ch 8*lg..8*lg+7 per super)

    // ---- B staging: threads 0..383 own one staged f2 position (sr, sp) ----
    const bool isStage = tid < NSTG;    // waves 0-5 stage; waves 6,7 compute-only
    const int sr = tid / BPOS;          // 0..15
    const int sp = tid % BPOS;          // 0..23
    const int bgh = h0 - 4 + sr, bgw = w0 - 4 + sp;
    const bool bok = isStage && (bgh >= 0) && (bgh < H_) && (bgw >= 0) && (bgw < W_);
    const int bghc = min(max(bgh, 0), H_ - 1);
    const int bgwc = min(max(bgw, 0), W_ - 1);
    const float* bbase = f2g + (size_t)b * CHW + (size_t)bghc * W_ + bgwc;
    // ---- A direct-from-global: lane (lp,lg) owns f1[h0+hs][w0+lp], ch 8lg+j ----
    const float* abase = f1g + (size_t)b * CHW + (size_t)(h0 + hs) * W_ + (w0 + lp)
                             + (size_t)(8 * lg) * HW;

    float bvr[16], avr[4];
    unsigned aw[4];                     // packed A frag (current super-chunk)
    float bn = 0.f, an = 0.f;

    auto issueB = [&](int c0) {
        if (!isStage) return;
#pragma unroll
        for (int j = 0; j < 16; ++j) bvr[j] = bbase[(size_t)(c0 + j) * HW];
    };
    auto issueA = [&](int c0) {         // c0 = 32*s + 4*h (8lg folded in abase)
#pragma unroll
        for (int j = 0; j < 4; ++j) avr[j] = abase[(size_t)(c0 + j) * HW];
    };

    auto stageB = [&](int buf, int h) {
        if (isStage) {
            unsigned u[8];
#pragma unroll
            for (int q = 0; q < 8; ++q) {
                const float x = bok ? bvr[2 * q] : 0.f;
                const float y = bok ? bvr[2 * q + 1] : 0.f;
                u[q] = pk2(x, y);
                bn = dot2f(u[q], u[q], bn);
            }
            char* dst = lds + buf * BUFB + sr * ROWB + sp * POSB + 32 * h;
            *reinterpret_cast<uint4*>(dst)      = make_uint4(u[0], u[1], u[2], u[3]);
            *reinterpret_cast<uint4*>(dst + 16) = make_uint4(u[4], u[5], u[6], u[7]);
        }
        const unsigned a0 = pk2(avr[0], avr[1]);
        const unsigned a1 = pk2(avr[2], avr[3]);
        an = dot2f(a0, a0, an);
        an = dot2f(a1, a1, an);
        aw[2 * h] = a0;
        aw[2 * h + 1] = a1;
    };

    f32x4 acc[9][2];                    // statically indexed ONLY (rule #20)
#pragma unroll
    for (int dy = 0; dy < 9; ++dy)
#pragma unroll
        for (int bt = 0; bt < 2; ++bt) acc[dy][bt] = (f32x4)0.f;

    const int fro = lp * POSB + lg * 16;   // b128 read offset (16B aligned)

    auto compute = [&](int buf) {
        const f16x8 afrag = __builtin_bit_cast(f16x8, make_uint4(aw[0], aw[1], aw[2], aw[3]));
        __builtin_amdgcn_s_setprio(1);
#pragma unroll
        for (int dy = 0; dy < 9; ++dy) {
            const char* rbase = lds + buf * BUFB + (hs + dy) * ROWB + fro;
            const f16x8 b0 = *reinterpret_cast<const f16x8*>(rbase);              // pos 0..15
            const f16x8 b1 = *reinterpret_cast<const f16x8*>(rbase + 8 * POSB);   // pos 8..23
            acc[dy][0] = __builtin_amdgcn_mfma_f32_16x16x32_f16(afrag, b0, acc[dy][0], 0, 0, 0);
            acc[dy][1] = __builtin_amdgcn_mfma_f32_16x16x32_f16(afrag, b1, acc[dy][1], 0, 0, 0);
        }
        __builtin_amdgcn_s_setprio(0);
    };

    // ---- pipeline: 8 super-chunks, halves staged into alternating buffers,
    //      raw lgkm-only barriers (2 per super), vmcnt never drained ----
    issueB(0);  issueA(0);
    stageB(0, 0);
    issueB(16); issueA(4);
    stageB(0, 1);
    issueB(32); issueA(32);
    publish_barrier();
    for (int s = 0; s < NSUP; ++s) {
        const int cur = s & 1, nxt = cur ^ 1;
        compute(cur);                       // reads buf cur + aw(s)
        if (s + 1 < NSUP) {
            stageB(nxt, 0);                 // super s+1 lo (loads long in flight)
            issueB(32 * (s + 1) + 16);
            issueA(32 * (s + 1) + 4);
        }
        publish_barrier();
        if (s + 1 < NSUP) {
            stageB(nxt, 1);                 // super s+1 hi
            if (s + 2 < NSUP) { issueB(32 * (s + 2)); issueA(32 * (s + 2)); }
        }
        publish_barrier();
    }

    // ---- norms (buf0 dead -> overlay) ----
    float* bnorm = reinterpret_cast<float*>(lds + BNOFF);   // [16][24]
    if (isStage) bnorm[tid] = bn;
    an += __shfl_xor(an, 16);
    an += __shfl_xor(an, 32);                               // full norm of pos lp
    const float inv1own = 1.0f / fmaxf(sqrtf(an), 1e-12f);
    float inv1v[4];
#pragma unroll
    for (int r = 0; r < 4; ++r) inv1v[r] = __shfl(inv1own, 4 * lg + r);
    __syncthreads();

    // ---- epilogue: overlapped-tile band select; acc selected by VALUE (no
    //      runtime array index — rule #20) ----
    const bool hiTile = (lg >> 1) != 0;     // lane-uniform within 16-lane group
    const int pos     = lp + (hiTile ? 8 : 0);
    const size_t obase = (size_t)b * 81 * HW;
#pragma unroll
    for (int pass = 0; pass < 2; ++pass) {
        if ((hs >> 2) == pass) {
            const int h4 = hs & 3;
#pragma unroll
            for (int dy = 0; dy < 9; ++dy) {
                const float nb = bnorm[(hs + dy) * BPOS + pos];
                const float v2 = 1.0f / fmaxf(sqrtf(nb), 1e-12f);
                const f32x4 a4 = hiTile ? acc[dy][1] : acc[dy][0];   // v_cndmask x4
#pragma unroll
                for (int r = 0; r < 4; ++r) {
                    const int mw  = 4 * lg + r;            // f1 w within tile
                    const int dxi = pos - mw;              // dx + 4
                    if (dxi >= 0 && dxi <= 8) {
                        float* orow = reinterpret_cast<float*>(lds)
                                    + ((dy * 9 + dxi) * 4 + h4) * OSTR;
                        orow[mw] = a4[r] * inv1v[r] * v2;
                    }
                }
            }
        }
        __syncthreads();
        for (int s = tid; s < 81 * 4 * 4; s += NTHREADS) {
            const int od = s >> 4;
            const int rem = s & 15;
            const int h4 = rem >> 2, q = rem & 3;
            const float4 v = *reinterpret_cast<const float4*>(
                reinterpret_cast<const float*>(lds) + (od * 4 + h4) * OSTR + q * 4);
            *reinterpret_cast<float4*>(outg + obase + (size_t)od * HW +
                                       (size_t)(h0 + pass * 4 + h4) * W_ + w0 + q * 4) = v;
        }
        if (pass == 0) __syncthreads();
    }
}

} // namespace

extern "C" void kernel_launch(void* const* d_in, const int* in_sizes, int n_in,
                              void* d_out, int out_size, void* d_ws, size_t ws_size,
                              hipStream_t stream)
{
    (void)in_sizes; (void)n_in; (void)d_ws; (void)ws_size; (void)out_size;
    const float* f1 = (const float*)d_in[0];
    const float* f2 = (const float*)d_in[1];
    float* out = (float*)d_out;

    dim3 grid(1536, 1, 1);     // 8 images x 16 hb x 12 wb, XCD-chunked in kernel
    dim3 block(NTHREADS);      // 512 threads = 8 waves (wave = h row)
    local_corr_mfma<<<grid, block, 0, stream>>>(f1, f2, out);
}